// Round 6
// baseline (277.914 us; speedup 1.0000x reference)
//
#include <hip/hip_runtime.h>

typedef __bf16 bf16x8 __attribute__((ext_vector_type(8)));
typedef float f32x4 __attribute__((ext_vector_type(4)));

constexpr int E = 1024;
constexpr int T = 8192;
constexpr size_t TE  = (size_t)T * E;
constexpr size_t WSZ = (size_t)E * E;

// 0.125 * log2(e): folded into Q at the GEMM epilogue so attention uses exp2.
#define QSCALE 0.18033688011112042f

__device__ __forceinline__ unsigned short f2bf(float f) {
    union { float f; unsigned int i; } x; x.f = f;
    unsigned int i = x.i;
    return (unsigned short)((i + 0x7fffu + ((i >> 16) & 1u)) >> 16);
}

// RTZ bf16 pair pack: result = [lo.hi16, hi.hi16]
__device__ __forceinline__ unsigned int pack_rtz(float lo, float hi) {
    return __builtin_amdgcn_perm(
        __builtin_bit_cast(unsigned int, hi),
        __builtin_bit_cast(unsigned int, lo), 0x07060302u);
}

__device__ __forceinline__ void gload16(const unsigned short* g, unsigned short* l) {
    __builtin_amdgcn_global_load_lds(
        (const __attribute__((address_space(1))) unsigned int*)g,
        (__attribute__((address_space(3))) unsigned int*)l, 16, 0, 0);
}

// ---------------------------------------------------------------------------
// One-shot fp32 -> bf16 conversion of x and the 4 weight matrices (~75 MB).
// ---------------------------------------------------------------------------
__global__ __launch_bounds__(256)
void cvt_kernel(const float* __restrict__ x,
                const float* __restrict__ w0, const float* __restrict__ w1,
                const float* __restrict__ w2, const float* __restrict__ w3,
                unsigned short* __restrict__ xb, unsigned short* __restrict__ wb)
{
    size_t i = ((size_t)blockIdx.x * 256 + threadIdx.x) * 8;
    const float* src;
    unsigned short* dst;
    if (i < TE) { src = x + i; dst = xb + i; }
    else {
        size_t j = i - TE;
        int w = (int)(j >> 20);
        size_t off = j & (WSZ - 1);
        src = (w == 0 ? w0 : w == 1 ? w1 : w == 2 ? w2 : w3) + off;
        dst = wb + ((size_t)w << 20) + off;
    }
    float4 a = *(const float4*)src;
    float4 b = *(const float4*)(src + 4);
    union { unsigned short u[8]; uint4 v; } p;
    p.u[0] = f2bf(a.x); p.u[1] = f2bf(a.y); p.u[2] = f2bf(a.z); p.u[3] = f2bf(a.w);
    p.u[4] = f2bf(b.x); p.u[5] = f2bf(b.y); p.u[6] = f2bf(b.z); p.u[7] = f2bf(b.w);
    *(uint4*)dst = p.v;
}

// ---------------------------------------------------------------------------
// R16 gemm_qkv body: 128x256 tile, 512 threads (8 waves, 2M x 4N, 64x64 per
// wave). Grid 64x12 = 768 blocks; LDS 48KB -> EXACTLY 3 blocks/CU x 256 CU
// = 768 slots. Removes the 1.5-round dispatch tail of the old 64x24 grid
// (1536 blocks / 1024 slots -> ~75% effective). Fragment geometry, row-XOR
// swizzle ((row>>1)&7 is pass-invariant: 64 === 0 mod 16 rows), and the
// m97 sync skeleton are carried over unchanged.
// ---------------------------------------------------------------------------
template <int MODE>   // 0: C^T bf16 out (Q/K)   2: per-head transposed V
__device__ __forceinline__ void gemm_body2(const unsigned short* __restrict__ X,
                                           const unsigned short* __restrict__ W,
                                           const float* __restrict__ bias,
                                           void* __restrict__ outp, int t0, int n0,
                                           float oscale)
{
    __shared__ unsigned short As[128 * 64];   // 16 KB
    __shared__ unsigned short Bs[256 * 64];   // 32 KB

    const int tid  = threadIdx.x;
    const int wave = tid >> 6;
    const int lane = tid & 63;
    const int quad = lane >> 4;
    const int l16  = lane & 15;
    const int wm   = wave >> 2;                      // 0..1 (M: 2 x 64)
    const int wn   = wave & 3;                       // 0..3 (N: 4 x 64)
    const int srow = tid >> 3;                       // staging row (0..63/pass)
    const int sch  = (tid & 7) ^ ((tid >> 4) & 7);   // swizzled source chunk
    const int fsw8 = (l16 >> 1) & 7;                 // fragment read swizzle

    f32x4 acc[4][4];
#pragma unroll
    for (int i = 0; i < 4; i++)
#pragma unroll
        for (int j = 0; j < 4; j++)
            acc[i][j] = (f32x4){0.f, 0.f, 0.f, 0.f};

    for (int k0 = 0; k0 < E; k0 += 64) {
#pragma unroll
        for (int p = 0; p < 2; p++)
            gload16(&X[(size_t)(t0 + p * 64 + srow) * E + k0 + sch * 8], &As[p * 4096 + tid * 8]);
#pragma unroll
        for (int p = 0; p < 4; p++)
            gload16(&W[(size_t)(n0 + p * 64 + srow) * E + k0 + sch * 8], &Bs[p * 4096 + tid * 8]);
        __syncthreads();

#pragma unroll
        for (int ks = 0; ks < 2; ks++) {
            const int rch = ((ks * 4 + quad) ^ fsw8) * 8;
            bf16x8 af[4], bfr[4];
#pragma unroll
            for (int i = 0; i < 4; i++)
                af[i] = *(const bf16x8*)&As[(wm * 64 + i * 16 + l16) * 64 + rch];
#pragma unroll
            for (int j = 0; j < 4; j++)
                bfr[j] = *(const bf16x8*)&Bs[(wn * 64 + j * 16 + l16) * 64 + rch];

#pragma unroll
            for (int i = 0; i < 4; i++)
#pragma unroll
                for (int j = 0; j < 4; j++) {
                    if (MODE == 2)
                        acc[i][j] = __builtin_amdgcn_mfma_f32_16x16x32_bf16(af[i], bfr[j], acc[i][j], 0, 0, 0);
                    else  // swapped: acc holds C^T (l16 = t, reg = n)
                        acc[i][j] = __builtin_amdgcn_mfma_f32_16x16x32_bf16(bfr[j], af[i], acc[i][j], 0, 0, 0);
                }
        }
        __syncthreads();
    }

    if (MODE == 2) {
#pragma unroll
        for (int j = 0; j < 4; j++) {
            const int gc = n0 + wn * 64 + j * 16 + l16;
            const float bj = bias[gc];
#pragma unroll
            for (int i = 0; i < 4; i++) {
                const int gr0 = t0 + wm * 64 + i * 16 + quad * 4;
                union { unsigned short u[4]; uint2 v; } o;
#pragma unroll
                for (int r = 0; r < 4; r++) o.u[r] = f2bf((acc[i][j][r] + bj) * oscale);
                unsigned short* vt = (unsigned short*)outp;
                *(uint2*)&vt[((size_t)((gr0 >> 11) * 16 + (gc >> 6)) * 64 + (gc & 63)) * 2048 + (gr0 & 2047)] = o.v;
            }
        }
    } else {
#pragma unroll
        for (int j = 0; j < 4; j++) {
            const int nb = n0 + wn * 64 + j * 16 + quad * 4;
            const float4 b4 = *(const float4*)&bias[nb];
#pragma unroll
            for (int i = 0; i < 4; i++) {
                const int t = t0 + wm * 64 + i * 16 + l16;
                union { unsigned short u[4]; uint2 v; } o;
                o.u[0] = f2bf((acc[i][j][0] + b4.x) * oscale);
                o.u[1] = f2bf((acc[i][j][1] + b4.y) * oscale);
                o.u[2] = f2bf((acc[i][j][2] + b4.z) * oscale);
                o.u[3] = f2bf((acc[i][j][3] + b4.w) * oscale);
                *(uint2*)&((unsigned short*)outp)[(size_t)t * E + nb] = o.v;
            }
        }
    }
}

// ---------------------------------------------------------------------------
// m97-style 128x128 body kept for gemm_out (512 blocks <= 1024 slots: no
// dispatch tail there; 2 blocks/CU uniform).
// ---------------------------------------------------------------------------
__device__ __forceinline__ void gemm_body_out(const unsigned short* __restrict__ X,
                                              const unsigned short* __restrict__ W,
                                              const float* __restrict__ bias,
                                              float* __restrict__ outp, int t0, int n0)
{
    __shared__ unsigned short As[128 * 64];
    __shared__ unsigned short Bs[128 * 64];

    const int tid  = threadIdx.x;
    const int wave = tid >> 6;
    const int lane = tid & 63;
    const int quad = lane >> 4;
    const int l16  = lane & 15;
    const int wm   = wave >> 1;
    const int wn   = wave & 1;
    const int srow = tid >> 3;
    const int sch  = (tid & 7) ^ ((tid >> 4) & 7);
    const int fsw8 = (l16 >> 1) & 7;

    f32x4 acc[4][4];
#pragma unroll
    for (int i = 0; i < 4; i++)
#pragma unroll
        for (int j = 0; j < 4; j++)
            acc[i][j] = (f32x4){0.f, 0.f, 0.f, 0.f};

    for (int k0 = 0; k0 < E; k0 += 64) {
#pragma unroll
        for (int j = 0; j < 4; j++) {
            gload16(&X[(size_t)(t0 + j * 32 + srow) * E + k0 + sch * 8], &As[j * 2048 + tid * 8]);
            gload16(&W[(size_t)(n0 + j * 32 + srow) * E + k0 + sch * 8], &Bs[j * 2048 + tid * 8]);
        }
        __syncthreads();

#pragma unroll
        for (int ks = 0; ks < 2; ks++) {
            const int rch = ((ks * 4 + quad) ^ fsw8) * 8;
            bf16x8 af[4], bfr[4];
#pragma unroll
            for (int i = 0; i < 4; i++)
                af[i] = *(const bf16x8*)&As[(wm * 64 + i * 16 + l16) * 64 + rch];
#pragma unroll
            for (int j = 0; j < 4; j++)
                bfr[j] = *(const bf16x8*)&Bs[(wn * 64 + j * 16 + l16) * 64 + rch];

#pragma unroll
            for (int i = 0; i < 4; i++)
#pragma unroll
                for (int j = 0; j < 4; j++)
                    acc[i][j] = __builtin_amdgcn_mfma_f32_16x16x32_bf16(bfr[j], af[i], acc[i][j], 0, 0, 0);
        }
        __syncthreads();
    }

#pragma unroll
    for (int j = 0; j < 4; j++) {
        const int nb = n0 + wn * 64 + j * 16 + quad * 4;
        const float4 b4 = *(const float4*)&bias[nb];
#pragma unroll
        for (int i = 0; i < 4; i++) {
            const int t = t0 + wm * 64 + i * 16 + l16;
            float4 o;
            o.x = acc[i][j][0] + b4.x;
            o.y = acc[i][j][1] + b4.y;
            o.z = acc[i][j][2] + b4.z;
            o.w = acc[i][j][3] + b4.w;
            *(float4*)&outp[(size_t)t * E + nb] = o;
        }
    }
}

__global__ __launch_bounds__(512, 6)
void gemm_qkv(const unsigned short* __restrict__ Xb, const unsigned short* __restrict__ Wb,
              const float* __restrict__ bq, const float* __restrict__ bk, const float* __restrict__ bv,
              unsigned short* __restrict__ Qb, unsigned short* __restrict__ Kb, unsigned short* __restrict__ VTb)
{
    const int t0 = blockIdx.x * 128;
    const int y = blockIdx.y;          // 0..11
    const int seg = y >> 2;
    const int n0 = (y & 3) * 256;
    const unsigned short* W = Wb + (size_t)seg * WSZ;
    if (seg == 0)      gemm_body2<0>(Xb, W, bq, Qb,  t0, n0, QSCALE);  // Q pre-scaled
    else if (seg == 1) gemm_body2<0>(Xb, W, bk, Kb,  t0, n0, 1.0f);
    else               gemm_body2<2>(Xb, W, bv, VTb, t0, n0, 1.0f);
}

__global__ __launch_bounds__(256, 4)
void gemm_out(const unsigned short* __restrict__ AOb, const unsigned short* __restrict__ Wob,
              const float* __restrict__ bo, float* __restrict__ out)
{
    gemm_body_out(AOb, Wob, bo, out, blockIdx.x * 128, blockIdx.y * 128);
}

// ---------------------------------------------------------------------------
// Flash attention, R16 = R14 verbatim (proven 79.8us; the R15 vf-hoist
// regressed twice and is reverted):
//  * KVBLK=64 ping-pong (32KB), stage-after-barrier prefetch-1, 1 barrier
//    per iter; 2 q-tiles/wave; P fully in registers via permlane32/16_swap;
//    l-sum on the MFMA pipe (ones-fragment); setprio(1) around PV.
//  * Grid (hb=64, qt=16): all 16 qt-blocks of one (b,h) land on one XCD.
// ---------------------------------------------------------------------------
__global__ __launch_bounds__(256, 4)
void attn_kernel(const unsigned short* __restrict__ Q,
                 const unsigned short* __restrict__ K,   // [T][E] token-major
                 const unsigned short* __restrict__ VT,  // [B*H][64][2048]
                 const float* __restrict__ hs,
                 unsigned short* __restrict__ AO)
{
    constexpr int S = 2048, H = 16;
    const int hb = blockIdx.x;          // 0..63
    const int qt = blockIdx.y;          // 0..15
    const int h  = hb >> 2;
    const int b  = hb & 3;

    const int tid  = threadIdx.x;
    const int wave = tid >> 6;
    const int lane = tid & 63;
    const int quad = lane >> 4;
    const int l16  = lane & 15;

    __shared__ unsigned short Kpl[2][2 * 64 * 32];   // [buf][plane][key*32+elem], 8KB/buf
    __shared__ unsigned short Vpl[2][64 * 64];       // [buf][d*64+key], 8KB/buf

    float mx = -1e30f;
    for (int i = 0; i < H; i++) mx = fmaxf(mx, hs[i]);
    float ss = 0.f;
    for (int i = 0; i < H; i++) ss += __expf(hs[i] - mx);
    const float head_imp = __expf(hs[h] - mx) / ss;

    const int base_t  = b * S;
    const int colbase = h * 64;
    const int q0 = qt * 128 + wave * 32;            // this wave's 32 q rows

    bf16x8 qf[2][2];
#pragma unroll
    for (int qi = 0; qi < 2; qi++)
#pragma unroll
        for (int c = 0; c < 2; c++)
            qf[qi][c] = *(const bf16x8*)&Q[(size_t)(base_t + q0 + qi * 16 + l16) * E + colbase + c * 32 + quad * 8];

    // ones A-fragment: A[m=l16][k] = (l16==0) ? 1 : 0  -> D[0][q] = sum_k P[q][k]
    union { unsigned short u[8]; bf16x8 v; } onesf;
    {
        const unsigned short ov = (l16 == 0) ? (unsigned short)0x3F80 : (unsigned short)0;
#pragma unroll
        for (int j = 0; j < 8; j++) onesf.u[j] = ov;
    }

    f32x4 oT[2][4];
#pragma unroll
    for (int qi = 0; qi < 2; qi++)
#pragma unroll
        for (int t = 0; t < 4; t++) oT[qi][t] = (f32x4){0.f, 0.f, 0.f, 0.f};
    f32x4 oT5[2];
    oT5[0] = (f32x4){0.f, 0.f, 0.f, 0.f};
    oT5[1] = (f32x4){0.f, 0.f, 0.f, 0.f};

    const int ksc  = (tid & 3) ^ ((tid >> 3) & 3);   // K staging chunk (4/row)
    const int vsc  = (tid & 7) ^ ((tid >> 4) & 7);   // V staging chunk (8/row)
    const int fsw  = (l16 >> 1) & 3;                 // 4-chunk fragment swizzle
    const int fsw8 = (l16 >> 1) & 7;                 // 8-chunk fragment swizzle
    const unsigned short* const vbase = VT + (size_t)(b * 16 + h) * 64 * 2048;

    // strength-reduced staging pointers
    const unsigned short* kg = &K[(size_t)(base_t + (tid >> 2)) * E + colbase + ksc * 8];
    const unsigned short* vg = &vbase[(size_t)(tid >> 3) * 2048 + vsc * 8];

    auto stage = [&](int bu) {
#pragma unroll
        for (int j = 0; j < 2; j++)
            gload16(kg + j * 32, &Kpl[bu][j * 2048 + tid * 8]);
#pragma unroll
        for (int j = 0; j < 2; j++)
            gload16(vg + (size_t)j * 32 * 2048, &Vpl[bu][j * 2048 + tid * 8]);
        kg += 64 * E;   // next tile: +64 token rows
        vg += 64;       // next tile: +64 key columns
    };

    stage(0);

#pragma unroll 2
    for (int kt = 0; kt < 32; kt++) {
        __syncthreads();   // own DMA for tile kt drained + all waves synced
        if (kt < 31) stage((kt + 1) & 1);
        const int cb = kt & 1;

        union { unsigned int w[4]; bf16x8 v; } pb[2][2];   // [qi][ks]
#pragma unroll
        for (int ks = 0; ks < 2; ks++) {
            unsigned int pw[2][4];
#pragma unroll
            for (int tkl = 0; tkl < 2; tkl++) {
                const int tk = ks * 2 + tkl;
                const int ko = (tk * 16 + l16) * 32 + (quad ^ fsw) * 8;
                bf16x8 kf0 = *(const bf16x8*)&Kpl[cb][ko];
                bf16x8 kf1 = *(const bf16x8*)&Kpl[cb][2048 + ko];
#pragma unroll
                for (int qi = 0; qi < 2; qi++) {
                    // S^T tile: D[m=key][n=q] = K·Q^T (0.125*log2e folded in Q)
                    f32x4 st = (f32x4){0.f, 0.f, 0.f, 0.f};
                    st = __builtin_amdgcn_mfma_f32_16x16x32_bf16(kf0, qf[qi][0], st, 0, 0, 0);
                    st = __builtin_amdgcn_mfma_f32_16x16x32_bf16(kf1, qf[qi][1], st, 0, 0, 0);
                    float p0 = __builtin_amdgcn_exp2f(st[0]);
                    float p1 = __builtin_amdgcn_exp2f(st[1]);
                    float p2 = __builtin_amdgcn_exp2f(st[2]);
                    float p3 = __builtin_amdgcn_exp2f(st[3]);
                    pw[qi][tkl * 2 + 0] = pack_rtz(p0, p1);   // keys ks*32+tkl*16+quad*4+{0,1}
                    pw[qi][tkl * 2 + 1] = pack_rtz(p2, p3);   // keys ks*32+tkl*16+quad*4+{2,3}
                }
            }
            // quad-permutation to B-fragment order: lane needs keys ks*32+quad*8..+7
#pragma unroll
            for (int qi = 0; qi < 2; qi++) {
                auto s1 = __builtin_amdgcn_permlane32_swap(pw[qi][0], pw[qi][2], false, false);
                auto s2 = __builtin_amdgcn_permlane32_swap(pw[qi][1], pw[qi][3], false, false);
                auto t1 = __builtin_amdgcn_permlane16_swap(s1[0], s1[1], false, false);
                auto t2 = __builtin_amdgcn_permlane16_swap(s2[0], s2[1], false, false);
                pb[qi][ks].w[0] = t1[0];   // keys +quad*8+{0,1}
                pb[qi][ks].w[1] = t2[0];   // keys +quad*8+{2,3}
                pb[qi][ks].w[2] = t1[1];   // keys +quad*8+{4,5}
                pb[qi][ks].w[3] = t2[1];   // keys +quad*8+{6,7}
            }
        }

        // PV: O^T[d][q] += V^T[d][key] . P[q][key]; l-sum rides the MFMA pipe
        __builtin_amdgcn_s_setprio(1);
#pragma unroll
        for (int tau = 0; tau < 4; tau++) {
#pragma unroll
            for (int ks = 0; ks < 2; ks++) {
                bf16x8 vf = *(const bf16x8*)&Vpl[cb][(tau * 16 + l16) * 64 + ((ks * 4 + quad) ^ fsw8) * 8];
#pragma unroll
                for (int qi = 0; qi < 2; qi++)
                    oT[qi][tau] = __builtin_amdgcn_mfma_f32_16x16x32_bf16(vf, pb[qi][ks].v, oT[qi][tau], 0, 0, 0);
            }
        }
#pragma unroll
        for (int qi = 0; qi < 2; qi++)
#pragma unroll
            for (int ks = 0; ks < 2; ks++)
                oT5[qi] = __builtin_amdgcn_mfma_f32_16x16x32_bf16(onesf.v, pb[qi][ks].v, oT5[qi], 0, 0, 0);
        __builtin_amdgcn_s_setprio(0);
    }

#pragma unroll
    for (int qi = 0; qi < 2; qi++) {
        // row-sum for q=l16 lives in lane (quad=0, l16), reg 0
        const float l = __shfl(oT5[qi][0], l16);
        const float inv = head_imp / l;
#pragma unroll
        for (int tau = 0; tau < 4; tau++) {
            union { unsigned short u[4]; uint2 v; } o;
#pragma unroll
            for (int r = 0; r < 4; r++) o.u[r] = f2bf(oT[qi][tau][r] * inv);
            *(uint2*)&AO[(size_t)(base_t + q0 + qi * 16 + l16) * E + colbase + tau * 16 + quad * 4] = o.v;
        }
    }
}

extern "C" void kernel_launch(void* const* d_in, const int* in_sizes, int n_in,
                              void* d_out, int out_size, void* d_ws, size_t ws_size,
                              hipStream_t stream)
{
    const float* x  = (const float*)d_in[0];
    const float* Wq = (const float*)d_in[1];
    const float* bq = (const float*)d_in[2];
    const float* Wk = (const float*)d_in[3];
    const float* bk = (const float*)d_in[4];
    const float* Wv = (const float*)d_in[5];
    const float* bv = (const float*)d_in[6];
    const float* Wo = (const float*)d_in[7];
    const float* bo = (const float*)d_in[8];
    const float* hs = (const float*)d_in[9];
    float* out = (float*)d_out;

    unsigned short* ws = (unsigned short*)d_ws;
    unsigned short* xb  = ws;
    unsigned short* wb  = ws + TE;
    unsigned short* Qb  = ws + TE + 4 * WSZ;
    unsigned short* AOb = Qb + TE;

    // Scratch for K / transposed-V: prefer workspace (avoids the harness
    // re-poisoning d_out inside the timed region); fall back to d_out.
    unsigned short* Kb;
    unsigned short* VTb;
    const size_t need_bytes = (5 * TE + 4 * WSZ) * sizeof(unsigned short);
    if (ws_size >= need_bytes) {
        Kb  = AOb + TE;
        VTb = Kb + TE;
    } else {
        Kb  = (unsigned short*)d_out;   // d_out as scratch (stream-ordered)
        VTb = Kb + TE;
    }

    hipLaunchKernelGGL(cvt_kernel, dim3(6144, 1, 1), dim3(256, 1, 1), 0, stream, x, Wq, Wk, Wv, Wo, xb, wb);
    hipLaunchKernelGGL(gemm_qkv, dim3(64, 12, 1), dim3(512, 1, 1), 0, stream, xb, wb, bq, bk, bv, Qb, Kb, VTb);
    hipLaunchKernelGGL(attn_kernel, dim3(64, 16, 1), dim3(256, 1, 1), 0, stream, Qb, Kb, VTb, hs, AOb);
    hipLaunchKernelGGL(gemm_out, dim3(64, 8, 1), dim3(256, 1, 1), 0, stream, AOb, wb + 3 * WSZ, bo, out);
}

// Round 7
// 255.392 us; speedup vs baseline: 1.0882x; 1.0882x over previous
//
#include <hip/hip_runtime.h>

typedef __bf16 bf16x8 __attribute__((ext_vector_type(8)));
typedef float f32x4 __attribute__((ext_vector_type(4)));

constexpr int E = 1024;
constexpr int T = 8192;
constexpr size_t TE  = (size_t)T * E;
constexpr size_t WSZ = (size_t)E * E;

// 0.125 * log2(e): folded into Q at the GEMM epilogue so attention uses exp2.
#define QSCALE 0.18033688011112042f

__device__ __forceinline__ unsigned short f2bf(float f) {
    union { float f; unsigned int i; } x; x.f = f;
    unsigned int i = x.i;
    return (unsigned short)((i + 0x7fffu + ((i >> 16) & 1u)) >> 16);
}

// RTZ bf16 pair pack: result = [lo.hi16, hi.hi16]
__device__ __forceinline__ unsigned int pack_rtz(float lo, float hi) {
    return __builtin_amdgcn_perm(
        __builtin_bit_cast(unsigned int, hi),
        __builtin_bit_cast(unsigned int, lo), 0x07060302u);
}

__device__ __forceinline__ void gload16(const unsigned short* g, unsigned short* l) {
    __builtin_amdgcn_global_load_lds(
        (const __attribute__((address_space(1))) unsigned int*)g,
        (__attribute__((address_space(3))) unsigned int*)l, 16, 0, 0);
}

// ---------------------------------------------------------------------------
// One-shot fp32 -> bf16 conversion of x and the 4 weight matrices (~75 MB).
// ---------------------------------------------------------------------------
__global__ __launch_bounds__(256)
void cvt_kernel(const float* __restrict__ x,
                const float* __restrict__ w0, const float* __restrict__ w1,
                const float* __restrict__ w2, const float* __restrict__ w3,
                unsigned short* __restrict__ xb, unsigned short* __restrict__ wb)
{
    size_t i = ((size_t)blockIdx.x * 256 + threadIdx.x) * 8;
    const float* src;
    unsigned short* dst;
    if (i < TE) { src = x + i; dst = xb + i; }
    else {
        size_t j = i - TE;
        int w = (int)(j >> 20);
        size_t off = j & (WSZ - 1);
        src = (w == 0 ? w0 : w == 1 ? w1 : w == 2 ? w2 : w3) + off;
        dst = wb + ((size_t)w << 20) + off;
    }
    float4 a = *(const float4*)src;
    float4 b = *(const float4*)(src + 4);
    union { unsigned short u[8]; uint4 v; } p;
    p.u[0] = f2bf(a.x); p.u[1] = f2bf(a.y); p.u[2] = f2bf(a.z); p.u[3] = f2bf(a.w);
    p.u[4] = f2bf(b.x); p.u[5] = f2bf(b.y); p.u[6] = f2bf(b.z); p.u[7] = f2bf(b.w);
    *(uint4*)dst = p.v;
}

// ---------------------------------------------------------------------------
// R17 gemm_qkv body: 128x256 tile, 512 threads (8 waves, 2M x 4N, 64x64 per
// wave). LDS BUG FIX (found via R16 counters, LDS_Block_Size=98304): the
// <0> and <2> template instantiations each carried their own static
// __shared__ As/Bs -> kernel LDS = SUM = 96KB -> 1 block/CU, Occupancy 20%,
// MfmaUtil 23. Now the CALLER owns one 48KB __shared__ block and passes
// As/Bs pointers (forceinline -> infer-address-spaces keeps ds_read).
// 48KB + VGPR~88 (4 waves/SIMD bin) -> 2 blocks/CU = 16 waves/CU, the
// m97-proven occupancy regime.
// ---------------------------------------------------------------------------
template <int MODE>   // 0: C^T bf16 out (Q/K)   2: per-head transposed V
__device__ __forceinline__ void gemm_body2(unsigned short* __restrict__ As,   // [128*64] LDS
                                           unsigned short* __restrict__ Bs,   // [256*64] LDS
                                           const unsigned short* __restrict__ X,
                                           const unsigned short* __restrict__ W,
                                           const float* __restrict__ bias,
                                           void* __restrict__ outp, int t0, int n0,
                                           float oscale)
{
    const int tid  = threadIdx.x;
    const int wave = tid >> 6;
    const int lane = tid & 63;
    const int quad = lane >> 4;
    const int l16  = lane & 15;
    const int wm   = wave >> 2;                      // 0..1 (M: 2 x 64)
    const int wn   = wave & 3;                       // 0..3 (N: 4 x 64)
    const int srow = tid >> 3;                       // staging row (0..63/pass)
    const int sch  = (tid & 7) ^ ((tid >> 4) & 7);   // swizzled source chunk
    const int fsw8 = (l16 >> 1) & 7;                 // fragment read swizzle

    f32x4 acc[4][4];
#pragma unroll
    for (int i = 0; i < 4; i++)
#pragma unroll
        for (int j = 0; j < 4; j++)
            acc[i][j] = (f32x4){0.f, 0.f, 0.f, 0.f};

    for (int k0 = 0; k0 < E; k0 += 64) {
#pragma unroll
        for (int p = 0; p < 2; p++)
            gload16(&X[(size_t)(t0 + p * 64 + srow) * E + k0 + sch * 8], &As[p * 4096 + tid * 8]);
#pragma unroll
        for (int p = 0; p < 4; p++)
            gload16(&W[(size_t)(n0 + p * 64 + srow) * E + k0 + sch * 8], &Bs[p * 4096 + tid * 8]);
        __syncthreads();

#pragma unroll
        for (int ks = 0; ks < 2; ks++) {
            const int rch = ((ks * 4 + quad) ^ fsw8) * 8;
            bf16x8 af[4], bfr[4];
#pragma unroll
            for (int i = 0; i < 4; i++)
                af[i] = *(const bf16x8*)&As[(wm * 64 + i * 16 + l16) * 64 + rch];
#pragma unroll
            for (int j = 0; j < 4; j++)
                bfr[j] = *(const bf16x8*)&Bs[(wn * 64 + j * 16 + l16) * 64 + rch];

#pragma unroll
            for (int i = 0; i < 4; i++)
#pragma unroll
                for (int j = 0; j < 4; j++) {
                    if (MODE == 2)
                        acc[i][j] = __builtin_amdgcn_mfma_f32_16x16x32_bf16(af[i], bfr[j], acc[i][j], 0, 0, 0);
                    else  // swapped: acc holds C^T (l16 = t, reg = n)
                        acc[i][j] = __builtin_amdgcn_mfma_f32_16x16x32_bf16(bfr[j], af[i], acc[i][j], 0, 0, 0);
                }
        }
        __syncthreads();
    }

    if (MODE == 2) {
#pragma unroll
        for (int j = 0; j < 4; j++) {
            const int gc = n0 + wn * 64 + j * 16 + l16;
            const float bj = bias[gc];
#pragma unroll
            for (int i = 0; i < 4; i++) {
                const int gr0 = t0 + wm * 64 + i * 16 + quad * 4;
                union { unsigned short u[4]; uint2 v; } o;
#pragma unroll
                for (int r = 0; r < 4; r++) o.u[r] = f2bf((acc[i][j][r] + bj) * oscale);
                unsigned short* vt = (unsigned short*)outp;
                *(uint2*)&vt[((size_t)((gr0 >> 11) * 16 + (gc >> 6)) * 64 + (gc & 63)) * 2048 + (gr0 & 2047)] = o.v;
            }
        }
    } else {
#pragma unroll
        for (int j = 0; j < 4; j++) {
            const int nb = n0 + wn * 64 + j * 16 + quad * 4;
            const float4 b4 = *(const float4*)&bias[nb];
#pragma unroll
            for (int i = 0; i < 4; i++) {
                const int t = t0 + wm * 64 + i * 16 + l16;
                union { unsigned short u[4]; uint2 v; } o;
                o.u[0] = f2bf((acc[i][j][0] + b4.x) * oscale);
                o.u[1] = f2bf((acc[i][j][1] + b4.y) * oscale);
                o.u[2] = f2bf((acc[i][j][2] + b4.z) * oscale);
                o.u[3] = f2bf((acc[i][j][3] + b4.w) * oscale);
                *(uint2*)&((unsigned short*)outp)[(size_t)t * E + nb] = o.v;
            }
        }
    }
}

// ---------------------------------------------------------------------------
// m97-style 128x128 body for gemm_out (single instantiation -> its static
// 32KB __shared__ is correct; 4 blocks/CU; 512 blocks, no dispatch tail).
// ---------------------------------------------------------------------------
__device__ __forceinline__ void gemm_body_out(const unsigned short* __restrict__ X,
                                              const unsigned short* __restrict__ W,
                                              const float* __restrict__ bias,
                                              float* __restrict__ outp, int t0, int n0)
{
    __shared__ unsigned short As[128 * 64];
    __shared__ unsigned short Bs[128 * 64];

    const int tid  = threadIdx.x;
    const int wave = tid >> 6;
    const int lane = tid & 63;
    const int quad = lane >> 4;
    const int l16  = lane & 15;
    const int wm   = wave >> 1;
    const int wn   = wave & 1;
    const int srow = tid >> 3;
    const int sch  = (tid & 7) ^ ((tid >> 4) & 7);
    const int fsw8 = (l16 >> 1) & 7;

    f32x4 acc[4][4];
#pragma unroll
    for (int i = 0; i < 4; i++)
#pragma unroll
        for (int j = 0; j < 4; j++)
            acc[i][j] = (f32x4){0.f, 0.f, 0.f, 0.f};

    for (int k0 = 0; k0 < E; k0 += 64) {
#pragma unroll
        for (int j = 0; j < 4; j++) {
            gload16(&X[(size_t)(t0 + j * 32 + srow) * E + k0 + sch * 8], &As[j * 2048 + tid * 8]);
            gload16(&W[(size_t)(n0 + j * 32 + srow) * E + k0 + sch * 8], &Bs[j * 2048 + tid * 8]);
        }
        __syncthreads();

#pragma unroll
        for (int ks = 0; ks < 2; ks++) {
            const int rch = ((ks * 4 + quad) ^ fsw8) * 8;
            bf16x8 af[4], bfr[4];
#pragma unroll
            for (int i = 0; i < 4; i++)
                af[i] = *(const bf16x8*)&As[(wm * 64 + i * 16 + l16) * 64 + rch];
#pragma unroll
            for (int j = 0; j < 4; j++)
                bfr[j] = *(const bf16x8*)&Bs[(wn * 64 + j * 16 + l16) * 64 + rch];

#pragma unroll
            for (int i = 0; i < 4; i++)
#pragma unroll
                for (int j = 0; j < 4; j++)
                    acc[i][j] = __builtin_amdgcn_mfma_f32_16x16x32_bf16(bfr[j], af[i], acc[i][j], 0, 0, 0);
        }
        __syncthreads();
    }

#pragma unroll
    for (int j = 0; j < 4; j++) {
        const int nb = n0 + wn * 64 + j * 16 + quad * 4;
        const float4 b4 = *(const float4*)&bias[nb];
#pragma unroll
        for (int i = 0; i < 4; i++) {
            const int t = t0 + wm * 64 + i * 16 + l16;
            float4 o;
            o.x = acc[i][j][0] + b4.x;
            o.y = acc[i][j][1] + b4.y;
            o.z = acc[i][j][2] + b4.z;
            o.w = acc[i][j][3] + b4.w;
            *(float4*)&outp[(size_t)t * E + nb] = o;
        }
    }
}

__global__ __launch_bounds__(512)
void gemm_qkv(const unsigned short* __restrict__ Xb, const unsigned short* __restrict__ Wb,
              const float* __restrict__ bq, const float* __restrict__ bk, const float* __restrict__ bv,
              unsigned short* __restrict__ Qb, unsigned short* __restrict__ Kb, unsigned short* __restrict__ VTb)
{
    // ONE shared allocation for all template instantiations (the R16 bug:
    // per-instantiation static __shared__ summed to 96KB).
    __shared__ unsigned short smem[(128 + 256) * 64];   // 48 KB
    unsigned short* As = smem;
    unsigned short* Bs = smem + 128 * 64;

    const int t0 = blockIdx.x * 128;
    const int y = blockIdx.y;          // 0..11
    const int seg = y >> 2;
    const int n0 = (y & 3) * 256;
    const unsigned short* W = Wb + (size_t)seg * WSZ;
    if (seg == 0)      gemm_body2<0>(As, Bs, Xb, W, bq, Qb,  t0, n0, QSCALE);  // Q pre-scaled
    else if (seg == 1) gemm_body2<0>(As, Bs, Xb, W, bk, Kb,  t0, n0, 1.0f);
    else               gemm_body2<2>(As, Bs, Xb, W, bv, VTb, t0, n0, 1.0f);
}

__global__ __launch_bounds__(256, 4)
void gemm_out(const unsigned short* __restrict__ AOb, const unsigned short* __restrict__ Wob,
              const float* __restrict__ bo, float* __restrict__ out)
{
    gemm_body_out(AOb, Wob, bo, out, blockIdx.x * 128, blockIdx.y * 128);
}

// ---------------------------------------------------------------------------
// Flash attention, R17 = R14 verbatim (proven 79.8us):
//  * KVBLK=64 ping-pong (32KB), stage-after-barrier prefetch-1, 1 barrier
//    per iter; 2 q-tiles/wave; P fully in registers via permlane32/16_swap;
//    l-sum on the MFMA pipe (ones-fragment); setprio(1) around PV.
//  * Grid (hb=64, qt=16): all 16 qt-blocks of one (b,h) land on one XCD.
// ---------------------------------------------------------------------------
__global__ __launch_bounds__(256, 4)
void attn_kernel(const unsigned short* __restrict__ Q,
                 const unsigned short* __restrict__ K,   // [T][E] token-major
                 const unsigned short* __restrict__ VT,  // [B*H][64][2048]
                 const float* __restrict__ hs,
                 unsigned short* __restrict__ AO)
{
    constexpr int S = 2048, H = 16;
    const int hb = blockIdx.x;          // 0..63
    const int qt = blockIdx.y;          // 0..15
    const int h  = hb >> 2;
    const int b  = hb & 3;

    const int tid  = threadIdx.x;
    const int wave = tid >> 6;
    const int lane = tid & 63;
    const int quad = lane >> 4;
    const int l16  = lane & 15;

    __shared__ unsigned short Kpl[2][2 * 64 * 32];   // [buf][plane][key*32+elem], 8KB/buf
    __shared__ unsigned short Vpl[2][64 * 64];       // [buf][d*64+key], 8KB/buf

    float mx = -1e30f;
    for (int i = 0; i < H; i++) mx = fmaxf(mx, hs[i]);
    float ss = 0.f;
    for (int i = 0; i < H; i++) ss += __expf(hs[i] - mx);
    const float head_imp = __expf(hs[h] - mx) / ss;

    const int base_t  = b * S;
    const int colbase = h * 64;
    const int q0 = qt * 128 + wave * 32;            // this wave's 32 q rows

    bf16x8 qf[2][2];
#pragma unroll
    for (int qi = 0; qi < 2; qi++)
#pragma unroll
        for (int c = 0; c < 2; c++)
            qf[qi][c] = *(const bf16x8*)&Q[(size_t)(base_t + q0 + qi * 16 + l16) * E + colbase + c * 32 + quad * 8];

    // ones A-fragment: A[m=l16][k] = (l16==0) ? 1 : 0  -> D[0][q] = sum_k P[q][k]
    union { unsigned short u[8]; bf16x8 v; } onesf;
    {
        const unsigned short ov = (l16 == 0) ? (unsigned short)0x3F80 : (unsigned short)0;
#pragma unroll
        for (int j = 0; j < 8; j++) onesf.u[j] = ov;
    }

    f32x4 oT[2][4];
#pragma unroll
    for (int qi = 0; qi < 2; qi++)
#pragma unroll
        for (int t = 0; t < 4; t++) oT[qi][t] = (f32x4){0.f, 0.f, 0.f, 0.f};
    f32x4 oT5[2];
    oT5[0] = (f32x4){0.f, 0.f, 0.f, 0.f};
    oT5[1] = (f32x4){0.f, 0.f, 0.f, 0.f};

    const int ksc  = (tid & 3) ^ ((tid >> 3) & 3);   // K staging chunk (4/row)
    const int vsc  = (tid & 7) ^ ((tid >> 4) & 7);   // V staging chunk (8/row)
    const int fsw  = (l16 >> 1) & 3;                 // 4-chunk fragment swizzle
    const int fsw8 = (l16 >> 1) & 7;                 // 8-chunk fragment swizzle
    const unsigned short* const vbase = VT + (size_t)(b * 16 + h) * 64 * 2048;

    // strength-reduced staging pointers
    const unsigned short* kg = &K[(size_t)(base_t + (tid >> 2)) * E + colbase + ksc * 8];
    const unsigned short* vg = &vbase[(size_t)(tid >> 3) * 2048 + vsc * 8];

    auto stage = [&](int bu) {
#pragma unroll
        for (int j = 0; j < 2; j++)
            gload16(kg + j * 32, &Kpl[bu][j * 2048 + tid * 8]);
#pragma unroll
        for (int j = 0; j < 2; j++)
            gload16(vg + (size_t)j * 32 * 2048, &Vpl[bu][j * 2048 + tid * 8]);
        kg += 64 * E;   // next tile: +64 token rows
        vg += 64;       // next tile: +64 key columns
    };

    stage(0);

#pragma unroll 2
    for (int kt = 0; kt < 32; kt++) {
        __syncthreads();   // own DMA for tile kt drained + all waves synced
        if (kt < 31) stage((kt + 1) & 1);
        const int cb = kt & 1;

        union { unsigned int w[4]; bf16x8 v; } pb[2][2];   // [qi][ks]
#pragma unroll
        for (int ks = 0; ks < 2; ks++) {
            unsigned int pw[2][4];
#pragma unroll
            for (int tkl = 0; tkl < 2; tkl++) {
                const int tk = ks * 2 + tkl;
                const int ko = (tk * 16 + l16) * 32 + (quad ^ fsw) * 8;
                bf16x8 kf0 = *(const bf16x8*)&Kpl[cb][ko];
                bf16x8 kf1 = *(const bf16x8*)&Kpl[cb][2048 + ko];
#pragma unroll
                for (int qi = 0; qi < 2; qi++) {
                    // S^T tile: D[m=key][n=q] = K·Q^T (0.125*log2e folded in Q)
                    f32x4 st = (f32x4){0.f, 0.f, 0.f, 0.f};
                    st = __builtin_amdgcn_mfma_f32_16x16x32_bf16(kf0, qf[qi][0], st, 0, 0, 0);
                    st = __builtin_amdgcn_mfma_f32_16x16x32_bf16(kf1, qf[qi][1], st, 0, 0, 0);
                    float p0 = __builtin_amdgcn_exp2f(st[0]);
                    float p1 = __builtin_amdgcn_exp2f(st[1]);
                    float p2 = __builtin_amdgcn_exp2f(st[2]);
                    float p3 = __builtin_amdgcn_exp2f(st[3]);
                    pw[qi][tkl * 2 + 0] = pack_rtz(p0, p1);   // keys ks*32+tkl*16+quad*4+{0,1}
                    pw[qi][tkl * 2 + 1] = pack_rtz(p2, p3);   // keys ks*32+tkl*16+quad*4+{2,3}
                }
            }
            // quad-permutation to B-fragment order: lane needs keys ks*32+quad*8..+7
#pragma unroll
            for (int qi = 0; qi < 2; qi++) {
                auto s1 = __builtin_amdgcn_permlane32_swap(pw[qi][0], pw[qi][2], false, false);
                auto s2 = __builtin_amdgcn_permlane32_swap(pw[qi][1], pw[qi][3], false, false);
                auto t1 = __builtin_amdgcn_permlane16_swap(s1[0], s1[1], false, false);
                auto t2 = __builtin_amdgcn_permlane16_swap(s2[0], s2[1], false, false);
                pb[qi][ks].w[0] = t1[0];   // keys +quad*8+{0,1}
                pb[qi][ks].w[1] = t2[0];   // keys +quad*8+{2,3}
                pb[qi][ks].w[2] = t1[1];   // keys +quad*8+{4,5}
                pb[qi][ks].w[3] = t2[1];   // keys +quad*8+{6,7}
            }
        }

        // PV: O^T[d][q] += V^T[d][key] . P[q][key]; l-sum rides the MFMA pipe
        __builtin_amdgcn_s_setprio(1);
#pragma unroll
        for (int tau = 0; tau < 4; tau++) {
#pragma unroll
            for (int ks = 0; ks < 2; ks++) {
                bf16x8 vf = *(const bf16x8*)&Vpl[cb][(tau * 16 + l16) * 64 + ((ks * 4 + quad) ^ fsw8) * 8];
#pragma unroll
                for (int qi = 0; qi < 2; qi++)
                    oT[qi][tau] = __builtin_amdgcn_mfma_f32_16x16x32_bf16(vf, pb[qi][ks].v, oT[qi][tau], 0, 0, 0);
            }
        }
#pragma unroll
        for (int qi = 0; qi < 2; qi++)
#pragma unroll
            for (int ks = 0; ks < 2; ks++)
                oT5[qi] = __builtin_amdgcn_mfma_f32_16x16x32_bf16(onesf.v, pb[qi][ks].v, oT5[qi], 0, 0, 0);
        __builtin_amdgcn_s_setprio(0);
    }

#pragma unroll
    for (int qi = 0; qi < 2; qi++) {
        // row-sum for q=l16 lives in lane (quad=0, l16), reg 0
        const float l = __shfl(oT5[qi][0], l16);
        const float inv = head_imp / l;
#pragma unroll
        for (int tau = 0; tau < 4; tau++) {
            union { unsigned short u[4]; uint2 v; } o;
#pragma unroll
            for (int r = 0; r < 4; r++) o.u[r] = f2bf(oT[qi][tau][r] * inv);
            *(uint2*)&AO[(size_t)(base_t + q0 + qi * 16 + l16) * E + colbase + tau * 16 + quad * 4] = o.v;
        }
    }
}

extern "C" void kernel_launch(void* const* d_in, const int* in_sizes, int n_in,
                              void* d_out, int out_size, void* d_ws, size_t ws_size,
                              hipStream_t stream)
{
    const float* x  = (const float*)d_in[0];
    const float* Wq = (const float*)d_in[1];
    const float* bq = (const float*)d_in[2];
    const float* Wk = (const float*)d_in[3];
    const float* bk = (const float*)d_in[4];
    const float* Wv = (const float*)d_in[5];
    const float* bv = (const float*)d_in[6];
    const float* Wo = (const float*)d_in[7];
    const float* bo = (const float*)d_in[8];
    const float* hs = (const float*)d_in[9];
    float* out = (float*)d_out;

    unsigned short* ws = (unsigned short*)d_ws;
    unsigned short* xb  = ws;
    unsigned short* wb  = ws + TE;
    unsigned short* Qb  = ws + TE + 4 * WSZ;
    unsigned short* AOb = Qb + TE;

    // Scratch for K / transposed-V: prefer workspace (avoids the harness
    // re-poisoning d_out inside the timed region); fall back to d_out.
    unsigned short* Kb;
    unsigned short* VTb;
    const size_t need_bytes = (5 * TE + 4 * WSZ) * sizeof(unsigned short);
    if (ws_size >= need_bytes) {
        Kb  = AOb + TE;
        VTb = Kb + TE;
    } else {
        Kb  = (unsigned short*)d_out;   // d_out as scratch (stream-ordered)
        VTb = Kb + TE;
    }

    hipLaunchKernelGGL(cvt_kernel, dim3(6144, 1, 1), dim3(256, 1, 1), 0, stream, x, Wq, Wk, Wv, Wo, xb, wb);
    hipLaunchKernelGGL(gemm_qkv, dim3(64, 12, 1), dim3(512, 1, 1), 0, stream, xb, wb, bq, bk, bv, Qb, Kb, VTb);
    hipLaunchKernelGGL(attn_kernel, dim3(64, 16, 1), dim3(256, 1, 1), 0, stream, Qb, Kb, VTb, hs, AOb);
    hipLaunchKernelGGL(gemm_out, dim3(64, 8, 1), dim3(256, 1, 1), 0, stream, AOb, wb + 3 * WSZ, bo, out);
}